// Round 16
// baseline (164.994 us; speedup 1.0000x reference)
//
#include <hip/hip_runtime.h>
#include <cstddef>
#include <cstdint>

#define Bn 4
#define Sn 4096
#define Hn 2048
#define Dn 256

typedef float f32x16 __attribute__((ext_vector_type(16)));
typedef short bf16x8 __attribute__((ext_vector_type(8)));

#define AS3 __attribute__((address_space(3)))
#define AS1 __attribute__((address_space(1)))

// log2(0.96875); gamma^256
#define L2G -0.045803689613125f
#define GC 2.9526131e-4f

__device__ __forceinline__ unsigned short f2bf(float f) {
  union { float f; unsigned int u; } a; a.f = f;
  unsigned int r = a.u + 0x7fffu + ((a.u >> 16) & 1u);
  return (unsigned short)(r >> 16);
}
__device__ __forceinline__ float bf2f(unsigned int b) {
  union { unsigned int u; float f; } a; a.u = b << 16;
  return a.f;
}

// ---------------------------------------------------------------------------
// prep: fused rt_build (blocks 0..2047) + wt_build (2048..2431).
// ---------------------------------------------------------------------------
__global__ __launch_bounds__(256) void prep_kernel(const float* __restrict__ wq,
                                                   const float* __restrict__ wk,
                                                   const float* __restrict__ wv,
                                                   unsigned short* __restrict__ wt,
                                                   float* __restrict__ rt) {
  __shared__ __align__(16) unsigned short T[64][72];
  const int bx = blockIdx.x;
  const int tid = threadIdx.x;
  if (bx < 2048) {
    const int g = bx * 256 + tid;
    const int s = g >> 7;
    const int jp = g & 127;
    const float invf = exp2f((float)jp * (-13.287712379549449f / 128.0f));
    float sn, cs;
    sincosf((float)s * invf, &sn, &cs);
    const float l2sv = log2f((2.0f * jp + 102.4f) * (1.0f / 358.4f));
    const float pw = ((float)s - 2048.0f) * (1.0f / 512.0f);
    const float tl = (float)(s & 255) * L2G;
    const float ex = pw * l2sv + tl;
    const float eq = exp2f(ex), ek = exp2f(-ex);
    float2* q = (float2*)rt;
    float2* k = (float2*)(rt + 4096 * 256);
    q[(size_t)s * 128 + jp] = make_float2(cs * eq, sn * eq);
    k[(size_t)s * 128 + jp] = make_float2(cs * ek, sn * ek);
  } else {
    const int bw = bx - 2048;
    const int k0 = (bw & 31) * 64;
    const int n0 = (bw >> 5) * 64;
    const float* w = (n0 < 256) ? wq : (n0 < 512 ? wk : wv);
    const int nc0 = n0 & 255;
#pragma unroll
    for (int it = 0; it < 2; ++it) {
      int flat = it * 256 + tid;
      int r = flat >> 3, c8 = flat & 7;
      const float* src = w + (size_t)(k0 + r) * 256 + nc0 + c8 * 8;
      float4 v0 = *(const float4*)src;
      float4 v1 = *(const float4*)(src + 4);
      T[c8 * 8 + 0][r] = f2bf(v0.x); T[c8 * 8 + 1][r] = f2bf(v0.y);
      T[c8 * 8 + 2][r] = f2bf(v0.z); T[c8 * 8 + 3][r] = f2bf(v0.w);
      T[c8 * 8 + 4][r] = f2bf(v1.x); T[c8 * 8 + 5][r] = f2bf(v1.y);
      T[c8 * 8 + 6][r] = f2bf(v1.z); T[c8 * 8 + 7][r] = f2bf(v1.w);
    }
    __syncthreads();
#pragma unroll
    for (int it = 0; it < 2; ++it) {
      int flat = it * 256 + tid;
      int nr = flat >> 3, kc8 = flat & 7;
      int n = n0 + nr;
      int kc_sw = kc8 ^ (n & 7);
      uint4 val = *(const uint4*)&T[nr][kc8 * 8];
      *(uint4*)((char*)wt + (size_t)n * 4096 + (size_t)k0 * 2 + kc_sw * 16) = val;
    }
  }
}

// ---------------------------------------------------------------------------
// proj9: proj6's per-wave geometry at BM=64 for exact load balance.
// Grid (256 m-tiles, 3 kinds) = 768 blocks = exactly 3 blocks/CU (LDS 40KB).
// 256 threads = 4 waves (1x4), wave tile 64x64, BK=64, mfma 32x32x16.
// A converted f32->bf16 in staging; B via global_load_lds (pre-swizzled wt).
// Fused table rotary epilogue.
//  q: -> qkv cols 0..255 ; k: -> qkv 256..511 (chunk-swizzled) + kt[b][d][t]
//  v: -> vt[b][d][t] only.
// ---------------------------------------------------------------------------
__global__ __launch_bounds__(256, 2) void proj9_kernel(const float* __restrict__ x,
                                                       const unsigned short* __restrict__ wt,
                                                       const float* __restrict__ rt,
                                                       unsigned short* __restrict__ qkv,
                                                       unsigned short* __restrict__ kt,
                                                       unsigned short* __restrict__ vt) {
  __shared__ __align__(16) char smem[40960];  // As 8KB @0, Bs 32KB @8192
  unsigned short* As = (unsigned short*)smem;
  const int tid = threadIdx.x;
  const int lane = tid & 63;
  const int wc = tid >> 6;           // wave 0..3 (1x4), wr = 0
  const int m0 = blockIdx.x * 64;
  const int kind = blockIdx.y;       // 0:q 1:k 2:v
  const int l31 = lane & 31, lh = lane >> 5;

  // A-staging thread mapping: row 0..63, col group of 16 f32
  const int arow = tid >> 2;
  const int acg = (tid & 3) << 4;
  const int asw = (arow & 7) << 4;

  f32x16 acc[2][2];
#pragma unroll
  for (int i = 0; i < 2; ++i)
#pragma unroll
    for (int j = 0; j < 2; ++j) acc[i][j] = 0.0f;

  for (int k0 = 0; k0 < Hn; k0 += 64) {
    // ---- A: issue f32 loads early ----
    const float* srcA = x + (size_t)(m0 + arow) * 2048 + k0 + acg;
    float4 f0 = ((const float4*)srcA)[0];
    float4 f1 = ((const float4*)srcA)[1];
    float4 f2 = ((const float4*)srcA)[2];
    float4 f3 = ((const float4*)srcA)[3];
    // ---- B: async DMA to LDS (8 chunks/thread-wave set) ----
    {
      AS3 char* ldsb = (AS3 char*)(smem + 8192);
#pragma unroll
      for (int i = 0; i < 8; ++i) {
        int ou = i * 4096 + wc * 1024;
        int o = ou + lane * 16;
        int row = o >> 7, colB = o & 127;
        const char* srcB = (const char*)wt + (size_t)(kind * 256 + row) * 4096 + k0 * 2 + colB;
        __builtin_amdgcn_global_load_lds((const AS1 unsigned int*)srcB,
                                         (AS3 unsigned int*)(ldsb + ou), 16, 0, 0);
      }
    }
    // ---- A: convert + swizzled LDS write ----
    {
      uint4 u0, u1;
      asm("v_cvt_pk_bf16_f32 %0, %1, %2" : "=v"(u0.x) : "v"(f0.x), "v"(f0.y));
      asm("v_cvt_pk_bf16_f32 %0, %1, %2" : "=v"(u0.y) : "v"(f0.z), "v"(f0.w));
      asm("v_cvt_pk_bf16_f32 %0, %1, %2" : "=v"(u0.z) : "v"(f1.x), "v"(f1.y));
      asm("v_cvt_pk_bf16_f32 %0, %1, %2" : "=v"(u0.w) : "v"(f1.z), "v"(f1.w));
      asm("v_cvt_pk_bf16_f32 %0, %1, %2" : "=v"(u1.x) : "v"(f2.x), "v"(f2.y));
      asm("v_cvt_pk_bf16_f32 %0, %1, %2" : "=v"(u1.y) : "v"(f2.z), "v"(f2.w));
      asm("v_cvt_pk_bf16_f32 %0, %1, %2" : "=v"(u1.z) : "v"(f3.x), "v"(f3.y));
      asm("v_cvt_pk_bf16_f32 %0, %1, %2" : "=v"(u1.w) : "v"(f3.z), "v"(f3.w));
      *(uint4*)((char*)As + arow * 128 + ((acg * 2) ^ asw)) = u0;
      *(uint4*)((char*)As + arow * 128 + ((acg * 2 + 16) ^ asw)) = u1;
    }
    __syncthreads();
#pragma unroll
    for (int kc = 0; kc < 4; ++kc) {
      const int kb = kc * 32 + lh * 16;
      bf16x8 a[2], b[2];
#pragma unroll
      for (int i = 0; i < 2; ++i) {
        int mr = i * 32 + l31;
        a[i] = *(const bf16x8*)((const char*)As + mr * 128 + (kb ^ ((mr & 7) << 4)));
        int nr = wc * 64 + i * 32 + l31;
        b[i] = *(const bf16x8*)(smem + 8192 + nr * 128 + (kb ^ ((nr & 7) << 4)));
      }
#pragma unroll
      for (int i = 0; i < 2; ++i)
#pragma unroll
        for (int j = 0; j < 2; ++j)
          acc[i][j] = __builtin_amdgcn_mfma_f32_32x32x16_bf16(a[i], b[j], acc[i][j], 0, 0, 0);
    }
    __syncthreads();
  }

  const int bidx = m0 >> 12;
  const int t0b = m0 & 4095;

  // ---- table rotary + scale for q/k ----
  if (kind < 2) {
    const float* rtb = rt + (size_t)kind * (4096 * 256);
    int jp[2];
#pragma unroll
    for (int j = 0; j < 2; ++j) jp[j] = (wc * 64 + j * 32 + l31) >> 1;
    const int odd = l31 & 1;
#pragma unroll
    for (int i = 0; i < 2; ++i)
#pragma unroll
      for (int reg = 0; reg < 16; ++reg) {
        const int mm = m0 + i * 32 + (reg & 3) + 8 * (reg >> 2) + 4 * lh;
        const int s = mm & (Sn - 1);
#pragma unroll
        for (int j = 0; j < 2; ++j) {
          const float2 cf = *(const float2*)(rtb + (size_t)s * 256 + jp[j] * 2);
          float v = acc[i][j][reg];
          float p = __shfl_xor(v, 1, 64);
          acc[i][j][reg] = odd ? (v * cf.x + p * cf.y) : (v * cf.x - p * cf.y);
        }
      }
  }

  // ---- stores ----
  if (kind == 0) {
#pragma unroll
    for (int i = 0; i < 2; ++i)
#pragma unroll
      for (int j = 0; j < 2; ++j)
#pragma unroll
        for (int reg = 0; reg < 16; ++reg) {
          int m = m0 + i * 32 + (reg & 3) + 8 * (reg >> 2) + 4 * lh;
          int n = wc * 64 + j * 32 + l31;
          qkv[(size_t)m * 768 + n] = f2bf(acc[i][j][reg]);
        }
  } else {
    if (kind == 1) {
#pragma unroll
      for (int i = 0; i < 2; ++i)
#pragma unroll
        for (int j = 0; j < 2; ++j)
#pragma unroll
          for (int reg = 0; reg < 16; ++reg) {
            int m = m0 + i * 32 + (reg & 3) + 8 * (reg >> 2) + 4 * lh;
            int d = wc * 64 + j * 32 + l31;
            qkv[(size_t)m * 768 + 256 + (d ^ ((m & 7) << 3))] = f2bf(acc[i][j][reg]);
          }
    }
    // transpose via LDS ([128 d][64 t] per half, 16KB, row stride 128B),
    // two 128-d halves; waves with (wc>>1)==h own half h.
    unsigned short* dst = (kind == 1) ? kt : vt;
#pragma unroll
    for (int h = 0; h < 2; ++h) {
      __syncthreads();
      if ((wc >> 1) == h) {
#pragma unroll
        for (int i = 0; i < 2; ++i)
#pragma unroll
          for (int j = 0; j < 2; ++j) {
            const int dl = (wc & 1) * 64 + j * 32 + l31;  // 0..127 within half
#pragma unroll
            for (int k8 = 0; k8 < 8; ++k8) {
              const int r0 = 2 * k8;
              const int t = i * 32 + (r0 & 3) + 8 * (r0 >> 2) + 4 * lh;  // 0..63, even
              unsigned int pk;
              asm("v_cvt_pk_bf16_f32 %0, %1, %2" : "=v"(pk)
                  : "v"(acc[i][j][r0]), "v"(acc[i][j][r0 + 1]));
              *(unsigned int*)(smem + dl * 128 + ((2 * t) ^ ((dl & 7) << 4))) = pk;
            }
          }
      }
      __syncthreads();
#pragma unroll
      for (int p = 0; p < 4; ++p) {
        const int fl = p * 256 + tid;          // 0..1023
        const int dl = fl >> 3, t8 = fl & 7;   // 128 d-rows x 8 uint4
        uint4 val = *(const uint4*)(smem + dl * 128 + ((t8 * 16) ^ ((dl & 7) << 4)));
        *(uint4*)(dst + (size_t)(bidx * 256 + h * 128 + dl) * 4096 + t0b + t8 * 8) = val;
      }
    }
  }
}

// ---------------------------------------------------------------------------
// wt_build (fallback path only)
// ---------------------------------------------------------------------------
__global__ __launch_bounds__(256) void wt_build(const float* __restrict__ wq,
                                                const float* __restrict__ wk,
                                                const float* __restrict__ wv,
                                                unsigned short* __restrict__ wt) {
  __shared__ __align__(16) unsigned short T[64][72];
  const int tid = threadIdx.x;
  const int k0 = blockIdx.x * 64;
  const int n0 = blockIdx.y * 64;
  const float* w = (n0 < 256) ? wq : (n0 < 512 ? wk : wv);
  const int nc0 = n0 & 255;
#pragma unroll
  for (int it = 0; it < 2; ++it) {
    int flat = it * 256 + tid;
    int r = flat >> 3, c8 = flat & 7;
    const float* src = w + (size_t)(k0 + r) * 256 + nc0 + c8 * 8;
    float4 v0 = *(const float4*)src;
    float4 v1 = *(const float4*)(src + 4);
    T[c8 * 8 + 0][r] = f2bf(v0.x); T[c8 * 8 + 1][r] = f2bf(v0.y);
    T[c8 * 8 + 2][r] = f2bf(v0.z); T[c8 * 8 + 3][r] = f2bf(v0.w);
    T[c8 * 8 + 4][r] = f2bf(v1.x); T[c8 * 8 + 5][r] = f2bf(v1.y);
    T[c8 * 8 + 6][r] = f2bf(v1.z); T[c8 * 8 + 7][r] = f2bf(v1.w);
  }
  __syncthreads();
#pragma unroll
  for (int it = 0; it < 2; ++it) {
    int flat = it * 256 + tid;
    int nr = flat >> 3, kc8 = flat & 7;
    int n = n0 + nr;
    int kc_sw = kc8 ^ (n & 7);
    uint4 val = *(const uint4*)&T[nr][kc8 * 8];
    *(uint4*)((char*)wt + (size_t)n * 4096 + (size_t)k0 * 2 + kc_sw * 16) = val;
  }
}

// ---------------------------------------------------------------------------
// proj (fallback small-ws): f32 A in-loop convert.
// ---------------------------------------------------------------------------
__global__ __launch_bounds__(256, 2) void proj_kernel(const float* __restrict__ x,
                                                      const unsigned short* __restrict__ wt,
                                                      unsigned short* __restrict__ qkv) {
  __shared__ __align__(16) unsigned short As[128 * 64];
  __shared__ __align__(16) unsigned short Bs[128 * 64];
  const int tid = threadIdx.x;
  const int lane = tid & 63;
  const int wid = tid >> 6;
  const int wr = wid >> 1, wc = wid & 1;
  const int m0 = blockIdx.x * 128;
  const int n0 = blockIdx.y * 128;
  const int l31 = lane & 31, lh = lane >> 5;

  f32x16 acc[2][2];
#pragma unroll
  for (int i = 0; i < 2; ++i)
#pragma unroll
    for (int j = 0; j < 2; ++j) acc[i][j] = 0.0f;

  for (int k0 = 0; k0 < Hn; k0 += 64) {
    {
      AS3 char* ldsb = (AS3 char*)Bs;
#pragma unroll
      for (int i = 0; i < 4; ++i) {
        int ou = i * 4096 + wid * 1024;
        int o = ou + lane * 16;
        int row = o >> 7, col = o & 127;
        const char* src = (const char*)wt + (size_t)(n0 + row) * 4096 + k0 * 2 + col;
        __builtin_amdgcn_global_load_lds((const AS1 unsigned int*)src,
                                         (AS3 unsigned int*)(ldsb + ou), 16, 0, 0);
      }
    }
#pragma unroll
    for (int i = 0; i < 4; ++i) {
      int o = i * 256 + tid;
      int row = o >> 3, c8 = o & 7;
      const float* src = x + (size_t)(m0 + row) * 2048 + k0 + c8 * 8;
      float4 v0 = *(const float4*)src;
      float4 v1 = *(const float4*)(src + 4);
      uint4 val;
      val.x = f2bf(v0.x) | ((unsigned int)f2bf(v0.y) << 16);
      val.y = f2bf(v0.z) | ((unsigned int)f2bf(v0.w) << 16);
      val.z = f2bf(v1.x) | ((unsigned int)f2bf(v1.y) << 16);
      val.w = f2bf(v1.z) | ((unsigned int)f2bf(v1.w) << 16);
      *(uint4*)((char*)As + row * 128 + ((c8 * 16) ^ ((row & 7) << 4))) = val;
    }
    __syncthreads();
#pragma unroll
    for (int kc = 0; kc < 4; ++kc) {
      const int kb = kc * 32 + lh * 16;
      bf16x8 a[2], b[2];
#pragma unroll
      for (int i = 0; i < 2; ++i) {
        int mr = wr * 64 + i * 32 + l31;
        a[i] = *(const bf16x8*)((const char*)As + mr * 128 + (kb ^ ((mr & 7) << 4)));
        int nr = wc * 64 + i * 32 + l31;
        b[i] = *(const bf16x8*)((const char*)Bs + nr * 128 + (kb ^ ((nr & 7) << 4)));
      }
#pragma unroll
      for (int i = 0; i < 2; ++i)
#pragma unroll
        for (int j = 0; j < 2; ++j)
          acc[i][j] = __builtin_amdgcn_mfma_f32_32x32x16_bf16(a[i], b[j], acc[i][j], 0, 0, 0);
    }
    __syncthreads();
  }
  const bool khalf = (n0 >= 256 && n0 < 512);
#pragma unroll
  for (int i = 0; i < 2; ++i)
#pragma unroll
    for (int j = 0; j < 2; ++j)
#pragma unroll
      for (int reg = 0; reg < 16; ++reg) {
        int m = m0 + wr * 64 + i * 32 + (reg & 3) + 8 * (reg >> 2) + 4 * lh;
        int n = n0 + wc * 64 + j * 32 + l31;
        if (khalf) n = 256 + ((n - 256) ^ ((m & 7) << 3));
        qkv[(size_t)m * 768 + n] = f2bf(acc[i][j][reg]);
      }
}

// ---------------------------------------------------------------------------
// xpos (fallback): rotary + chunk decay folding, in place on bf16 qkv.
// ---------------------------------------------------------------------------
__global__ __launch_bounds__(256) void xpos_kernel(unsigned short* __restrict__ qkv) {
  const int g = blockIdx.x * 256 + threadIdx.x;
  const int m = g >> 5;
  const int c = g & 31;
  const float s = (float)(m & (Sn - 1));
  unsigned short* qrow = qkv + (size_t)m * 768;
  const int csw = c ^ (m & 7);
  uint4 qv = *(uint4*)(qrow + c * 8);
  uint4 kv = *(uint4*)(qrow + 256 + csw * 8);
  unsigned int* qu = (unsigned int*)&qv;
  unsigned int* ku = (unsigned int*)&kv;
  const float pw = (s - 2048.0f) * (1.0f / 512.0f);
  const float gp = exp2f((float)(m & 255) * L2G);
#pragma unroll
  for (int p = 0; p < 4; ++p) {
    const int jp = c * 4 + p;
    const float invf = exp2f((float)jp * (-13.287712379549449f / 128.0f));
    float sn, cs;
    sincosf(s * invf, &sn, &cs);
    const float sv = (2.0f * jp + 102.4f) * (1.0f / 358.4f);
    const float scq = exp2f(pw * log2f(sv)) * gp;
    const float sci = 1.0f / scq;
    float q0 = bf2f(qu[p] & 0xffffu), q1 = bf2f(qu[p] >> 16);
    float k0 = bf2f(ku[p] & 0xffffu), k1 = bf2f(ku[p] >> 16);
    float q0r = (q0 * cs - q1 * sn) * scq;
    float q1r = (q1 * cs + q0 * sn) * scq;
    float k0r = (k0 * cs - k1 * sn) * sci;
    float k1r = (k1 * cs + k0 * sn) * sci;
    qu[p] = f2bf(q0r) | ((unsigned int)f2bf(q1r) << 16);
    ku[p] = f2bf(k0r) | ((unsigned int)f2bf(k1r) << 16);
  }
  *(uint4*)(qrow + c * 8) = qv;
  *(uint4*)(qrow + 256 + csw * 8) = kv;
}

// ---------------------------------------------------------------------------
// kvt (fallback): kt[b][d][t], vt[b][d][t] from qkv.
// ---------------------------------------------------------------------------
__global__ __launch_bounds__(256) void kvt_build(const unsigned short* __restrict__ qkv,
                                                 unsigned short* __restrict__ kt,
                                                 unsigned short* __restrict__ vt) {
  __shared__ __align__(16) unsigned short Tk[64][72];
  __shared__ __align__(16) unsigned short Tv[64][72];
  const int tid = threadIdx.x;
  const int t0 = blockIdx.x * 64;
  const int d0 = blockIdx.y * 64;
  const int b = blockIdx.z;
  const size_t rowb = ((size_t)b * Sn + t0) * 1536;
#pragma unroll
  for (int it = 0; it < 2; ++it) {
    int flat = it * 256 + tid;
    int r = flat >> 3, c8 = flat & 7;
    int kc = (d0 >> 3) + c8;
    int kcs = kc ^ (r & 7);
    uint4 kvv = *(const uint4*)((const char*)qkv + rowb + (size_t)r * 1536 + 512 + kcs * 16);
    uint4 vvv = *(const uint4*)((const char*)qkv + rowb + (size_t)r * 1536 + 1024 + (size_t)(d0 + c8 * 8) * 2);
    const unsigned short* ke = (const unsigned short*)&kvv;
    const unsigned short* ve = (const unsigned short*)&vvv;
#pragma unroll
    for (int e = 0; e < 8; ++e) { Tk[c8 * 8 + e][r] = ke[e]; Tv[c8 * 8 + e][r] = ve[e]; }
  }
  __syncthreads();
#pragma unroll
  for (int it = 0; it < 2; ++it) {
    int flat = it * 256 + tid;
    int dr = flat >> 3, tc8 = flat & 7;
    *(uint4*)(kt + (size_t)(b * 256 + d0 + dr) * 4096 + t0 + tc8 * 8) = *(const uint4*)&Tk[dr][tc8 * 8];
    *(uint4*)(vt + (size_t)(b * 256 + d0 + dr) * 4096 + t0 + tc8 * 8) = *(const uint4*)&Tv[dr][tc8 * 8];
  }
}

// ---------------------------------------------------------------------------
// mbuild: Mt[b][j][d2][d1] = sum_t V[t][d2] * K~[t][d1], bf16 out.
// ---------------------------------------------------------------------------
__global__ __launch_bounds__(256) void mbuild_kernel(const unsigned short* __restrict__ kt,
                                                     const unsigned short* __restrict__ vt,
                                                     unsigned short* __restrict__ mt) {
  const int tid = threadIdx.x;
  const int lane = tid & 63;
  const int wid = tid >> 6;
  const int l31 = lane & 31, lh = lane >> 5;
  const int jc = blockIdx.x;
  const int quad = blockIdx.y;
  const int b = blockIdx.z;
  const int d2w = ((quad >> 1) * 2 + (wid >> 1)) * 64;
  const int d1w = ((quad & 1) * 2 + (wid & 1)) * 64;
  const size_t tb = (size_t)jc * 256;

  f32x16 acc[2][2];
#pragma unroll
  for (int i = 0; i < 2; ++i)
#pragma unroll
    for (int j = 0; j < 2; ++j) acc[i][j] = 0.0f;

#pragma unroll 2
  for (int dc = 0; dc < 16; ++dc) {
    const int ko = dc * 32 + lh * 16;
    bf16x8 a[2], bb[2];
#pragma unroll
    for (int i = 0; i < 2; ++i) {
      a[i]  = *(const bf16x8*)((const char*)vt + ((size_t)(b * 256 + d2w + i * 32 + l31) * 4096 + tb) * 2 + ko);
      bb[i] = *(const bf16x8*)((const char*)kt + ((size_t)(b * 256 + d1w + i * 32 + l31) * 4096 + tb) * 2 + ko);
    }
#pragma unroll
    for (int i = 0; i < 2; ++i)
#pragma unroll
      for (int j = 0; j < 2; ++j)
        acc[i][j] = __builtin_amdgcn_mfma_f32_32x32x16_bf16(a[i], bb[j], acc[i][j], 0, 0, 0);
  }
  unsigned short* dst = mt + ((size_t)(b * 16 + jc) << 16);
#pragma unroll
  for (int i = 0; i < 2; ++i)
#pragma unroll
    for (int j = 0; j < 2; ++j)
#pragma unroll
      for (int reg = 0; reg < 16; ++reg) {
        int row = d2w + i * 32 + (reg & 3) + 8 * (reg >> 2) + 4 * lh;
        int col = d1w + j * 32 + l31;
        dst[row * 256 + col] = f2bf(acc[i][j][reg]);
      }
}

// ---------------------------------------------------------------------------
// scan: S_j = GC*(S_{j-1} + M_{j-1}), in place to slot j-1 (bf16).
// ---------------------------------------------------------------------------
__global__ __launch_bounds__(256) void scan_kernel(unsigned short* __restrict__ mt) {
  const int e0 = (blockIdx.x * 256 + threadIdx.x) * 4;
  const int b = blockIdx.y;
  unsigned short* base = mt + ((size_t)b << 20);
  float s0 = 0.f, s1 = 0.f, s2 = 0.f, s3 = 0.f;
  for (int j = 1; j < 16; ++j) {
    unsigned short* p = base + ((size_t)(j - 1) << 16) + e0;
    uint2 mv = *(const uint2*)p;
    s0 = GC * (s0 + bf2f(mv.x & 0xffffu));
    s1 = GC * (s1 + bf2f(mv.x >> 16));
    s2 = GC * (s2 + bf2f(mv.y & 0xffffu));
    s3 = GC * (s3 + bf2f(mv.y >> 16));
    uint2 w;
    w.x = f2bf(s0) | ((unsigned int)f2bf(s1) << 16);
    w.y = f2bf(s2) | ((unsigned int)f2bf(s3) << 16);
    *(uint2*)p = w;
  }
}

// ---------------------------------------------------------------------------
// retc: out = Q~ @ S_j (cross) + causal-intra(Q~ K~^T) @ V
// Grid (128 st32, 2 dh, 4 b) = 1024 blocks; 4 waves split cross-dc /
// intra-parity. Two-stage LDS combine. (R7-proven configuration.)
// ---------------------------------------------------------------------------
__global__ __launch_bounds__(256, 2) void retc_kernel(const unsigned short* __restrict__ qkv,
                                                      const unsigned short* __restrict__ vt,
                                                      const unsigned short* __restrict__ mt,
                                                      float* __restrict__ out) {
  __shared__ float cmb[2][32][128];
  const int tid = threadIdx.x;
  const int lane = tid & 63;
  const int tw = tid >> 6;
  const int l31 = lane & 31, lh = lane >> 5;
  const int st = blockIdx.x;
  const int dh = blockIdx.y;
  const int b = blockIdx.z;
  const int j = st >> 3;
  const int base = st & ~7;
  const int s0 = st * 32;
  const int d0 = dh * 128;

  bf16x8 qf[16];
  {
    const char* qrow = (const char*)qkv + ((size_t)b * Sn + s0 + l31) * 1536;
#pragma unroll
    for (int dc = 0; dc < 16; ++dc)
      qf[dc] = *(const bf16x8*)(qrow + dc * 32 + lh * 16);
  }

  f32x16 acc[4];
#pragma unroll
  for (int i = 0; i < 4; ++i) acc[i] = 0.0f;

  if (j > 0) {
    const char* Sj = (const char*)mt + ((size_t)(b * 16 + j - 1) << 17);
#pragma unroll
    for (int dcl = 0; dcl < 4; ++dcl) {
      const int dc = tw * 4 + dcl;
#pragma unroll
      for (int g = 0; g < 4; ++g) {
        const int d2 = d0 + g * 32 + l31;
        bf16x8 sbf = *(const bf16x8*)(Sj + (size_t)d2 * 512 + dc * 32 + lh * 16);
        acc[g] = __builtin_amdgcn_mfma_f32_32x32x16_bf16(qf[dc], sbf, acc[g], 0, 0, 0);
      }
    }
  }

  const int sg = s0 + l31;
  const int ksw = (l31 & 7) << 4;
  for (int tt = base; tt <= st; ++tt) {
    if (((tt - base) & 3) != tw) continue;
    const bool msk = (tt == st);
    const int t0 = tt * 32;

    f32x16 sacc = 0.0f;
    const char* krow = (const char*)qkv + ((size_t)b * Sn + t0 + l31) * 1536 + 512;
    __builtin_amdgcn_s_setprio(1);
#pragma unroll
    for (int dc = 0; dc < 16; ++dc) {
      bf16x8 kf = *(const bf16x8*)(krow + ((dc * 32 + lh * 16) ^ ksw));
      sacc = __builtin_amdgcn_mfma_f32_32x32x16_bf16(kf, qf[dc], sacc, 0, 0, 0);
    }
    __builtin_amdgcn_s_setprio(0);

    unsigned int P[8];
#pragma unroll
    for (int k = 0; k < 8; ++k) {
      const int r0 = 2 * k;
      float f0 = sacc[r0], f1 = sacc[r0 + 1];
      if (msk) {
        const int tg0 = t0 + (r0 & 3) + 8 * (r0 >> 2) + 4 * lh;
        f0 = (sg - tg0 >= 0) ? f0 : 0.0f;
        f1 = (sg - tg0 - 1 >= 0) ? f1 : 0.0f;
      }
      unsigned int pk;
      asm("v_cvt_pk_bf16_f32 %0, %1, %2" : "=v"(pk) : "v"(f0), "v"(f1));
      P[k] = pk;
    }
    asm volatile("v_permlane32_swap_b32 %0, %1" : "+v"(P[0]), "+v"(P[2]));
    asm volatile("v_permlane32_swap_b32 %0, %1" : "+v"(P[1]), "+v"(P[3]));
    asm volatile("v_permlane32_swap_b32 %0, %1" : "+v"(P[4]), "+v"(P[6]));
    asm volatile("v_permlane32_swap_b32 %0, %1" : "+v"(P[5]), "+v"(P[7]));

    __builtin_amdgcn_s_setprio(1);
#pragma unroll
    for (int kc = 0; kc < 2; ++kc) {
      uint4 pw;
      pw.x = P[kc * 4 + 0]; pw.y = P[kc * 4 + 1];
      pw.z = P[kc * 4 + 2]; pw.w = P[kc * 4 + 3];
      bf16x8 pf = *(const bf16x8*)&pw;
#pragma unroll
      for (int g = 0; g < 4; ++g) {
        const int d = d0 + g * 32 + l31;
        bf16x8 vf = *(const bf16x8*)((const char*)vt +
            ((size_t)(b * 256 + d) * 4096 + t0) * 2 + kc * 32 + lh * 16);
        acc[g] = __builtin_amdgcn_mfma_f32_32x32x16_bf16(pf, vf, acc[g], 0, 0, 0);
      }
    }
    __builtin_amdgcn_s_setprio(0);
  }

  if (tw >= 2) {
#pragma unroll
    for (int g = 0; g < 4; ++g)
#pragma unroll
      for (int reg = 0; reg < 16; ++reg) {
        int sl = (reg & 3) + 8 * (reg >> 2) + 4 * lh;
        cmb[tw - 2][sl][g * 32 + l31] = acc[g][reg];
      }
  }
  __syncthreads();
  if (tw < 2) {
#pragma unroll
    for (int g = 0; g < 4; ++g)
#pragma unroll
      for (int reg = 0; reg < 16; ++reg) {
        int sl = (reg & 3) + 8 * (reg >> 2) + 4 * lh;
        acc[g][reg] += cmb[tw][sl][g * 32 + l31];
      }
  }
  __syncthreads();
  if (tw == 1) {
#pragma unroll
    for (int g = 0; g < 4; ++g)
#pragma unroll
      for (int reg = 0; reg < 16; ++reg) {
        int sl = (reg & 3) + 8 * (reg >> 2) + 4 * lh;
        cmb[0][sl][g * 32 + l31] = acc[g][reg];
      }
  }
  __syncthreads();
  if (tw == 0) {
#pragma unroll
    for (int g = 0; g < 4; ++g)
#pragma unroll
      for (int reg = 0; reg < 16; ++reg) {
        int sl = (reg & 3) + 8 * (reg >> 2) + 4 * lh;
        int c = g * 32 + l31;
        out[((size_t)(b * Sn + s0 + sl)) * 256 + d0 + c] = acc[g][reg] + cmb[0][sl][c];
      }
  }
}

// ---------------------------------------------------------------------------
extern "C" void kernel_launch(void* const* d_in, const int* in_sizes, int n_in,
                              void* d_out, int out_size, void* d_ws, size_t ws_size,
                              hipStream_t stream) {
  (void)in_sizes; (void)n_in; (void)out_size;
  const float* x  = (const float*)d_in[0];
  const float* wq = (const float*)d_in[1];
  const float* wk = (const float*)d_in[2];
  const float* wv = (const float*)d_in[3];
  float* out = (float*)d_out;
  char* ws = (char*)d_ws;

  unsigned short* qkv = (unsigned short*)(ws);              // 25,165,824 B
  unsigned short* vt  = (unsigned short*)(ws + 25165824);   //  8,388,608 B
  unsigned short* kt  = (unsigned short*)(ws + 33554432);   //  8,388,608 B
  unsigned short* mt  = (unsigned short*)(ws + 41943040);   //  8,388,608 B

  const size_t NEED_BIG = 128974848;  // wt@117440512 + rt@120586240
  if (ws_size >= NEED_BIG) {
    unsigned short* wt = (unsigned short*)(ws + 117440512);  //  3,145,728 B
    float*          rtab = (float*)(ws + 120586240);         //  8,388,608 B
    prep_kernel<<<2432, 256, 0, stream>>>(wq, wk, wv, wt, rtab);
    proj9_kernel<<<dim3(256, 3), 256, 0, stream>>>(x, wt, rtab, qkv, kt, vt);
  } else {
    unsigned short* wt = (unsigned short*)(ws + 41943040);  // alias mt (dead before mbuild)
    wt_build<<<dim3(32, 12), 256, 0, stream>>>(wq, wk, wv, wt);
    proj_kernel<<<dim3(128, 6), 256, 0, stream>>>(x, wt, qkv);
    xpos_kernel<<<2048, 256, 0, stream>>>(qkv);
    kvt_build<<<dim3(64, 4, 4), 256, 0, stream>>>(qkv, kt, vt);
  }
  mbuild_kernel<<<dim3(16, 4, 4), 256, 0, stream>>>(kt, vt, mt);
  scan_kernel<<<dim3(64, 4), 256, 0, stream>>>(mt);
  retc_kernel<<<dim3(128, 2, 4), 256, 0, stream>>>(qkv, vt, mt, out);
}

// Round 17
// 161.265 us; speedup vs baseline: 1.0231x; 1.0231x over previous
//
#include <hip/hip_runtime.h>
#include <cstddef>
#include <cstdint>

#define Bn 4
#define Sn 4096
#define Hn 2048
#define Dn 256

typedef float f32x16 __attribute__((ext_vector_type(16)));
typedef short bf16x8 __attribute__((ext_vector_type(8)));

#define AS3 __attribute__((address_space(3)))
#define AS1 __attribute__((address_space(1)))

// log2(0.96875); gamma^256
#define L2G -0.045803689613125f
#define GC 2.9526131e-4f

__device__ __forceinline__ unsigned short f2bf(float f) {
  union { float f; unsigned int u; } a; a.f = f;
  unsigned int r = a.u + 0x7fffu + ((a.u >> 16) & 1u);
  return (unsigned short)(r >> 16);
}
__device__ __forceinline__ float bf2f(unsigned int b) {
  union { unsigned int u; float f; } a; a.u = b << 16;
  return a.f;
}

// ---------------------------------------------------------------------------
// prep: fused rt_build (blocks 0..2047) + wt_build (2048..2431).
// ---------------------------------------------------------------------------
__global__ __launch_bounds__(256) void prep_kernel(const float* __restrict__ wq,
                                                   const float* __restrict__ wk,
                                                   const float* __restrict__ wv,
                                                   unsigned short* __restrict__ wt,
                                                   float* __restrict__ rt) {
  __shared__ __align__(16) unsigned short T[64][72];
  const int bx = blockIdx.x;
  const int tid = threadIdx.x;
  if (bx < 2048) {
    const int g = bx * 256 + tid;
    const int s = g >> 7;
    const int jp = g & 127;
    const float invf = exp2f((float)jp * (-13.287712379549449f / 128.0f));
    float sn, cs;
    sincosf((float)s * invf, &sn, &cs);
    const float l2sv = log2f((2.0f * jp + 102.4f) * (1.0f / 358.4f));
    const float pw = ((float)s - 2048.0f) * (1.0f / 512.0f);
    const float tl = (float)(s & 255) * L2G;
    const float ex = pw * l2sv + tl;
    const float eq = exp2f(ex), ek = exp2f(-ex);
    float2* q = (float2*)rt;
    float2* k = (float2*)(rt + 4096 * 256);
    q[(size_t)s * 128 + jp] = make_float2(cs * eq, sn * eq);
    k[(size_t)s * 128 + jp] = make_float2(cs * ek, sn * ek);
  } else {
    const int bw = bx - 2048;
    const int k0 = (bw & 31) * 64;
    const int n0 = (bw >> 5) * 64;
    const float* w = (n0 < 256) ? wq : (n0 < 512 ? wk : wv);
    const int nc0 = n0 & 255;
#pragma unroll
    for (int it = 0; it < 2; ++it) {
      int flat = it * 256 + tid;
      int r = flat >> 3, c8 = flat & 7;
      const float* src = w + (size_t)(k0 + r) * 256 + nc0 + c8 * 8;
      float4 v0 = *(const float4*)src;
      float4 v1 = *(const float4*)(src + 4);
      T[c8 * 8 + 0][r] = f2bf(v0.x); T[c8 * 8 + 1][r] = f2bf(v0.y);
      T[c8 * 8 + 2][r] = f2bf(v0.z); T[c8 * 8 + 3][r] = f2bf(v0.w);
      T[c8 * 8 + 4][r] = f2bf(v1.x); T[c8 * 8 + 5][r] = f2bf(v1.y);
      T[c8 * 8 + 6][r] = f2bf(v1.z); T[c8 * 8 + 7][r] = f2bf(v1.w);
    }
    __syncthreads();
#pragma unroll
    for (int it = 0; it < 2; ++it) {
      int flat = it * 256 + tid;
      int nr = flat >> 3, kc8 = flat & 7;
      int n = n0 + nr;
      int kc_sw = kc8 ^ (n & 7);
      uint4 val = *(const uint4*)&T[nr][kc8 * 8];
      *(uint4*)((char*)wt + (size_t)n * 4096 + (size_t)k0 * 2 + kc_sw * 16) = val;
    }
  }
}

// ---------------------------------------------------------------------------
// proj6 (R15-proven best, 161.7us build): BM=128 x BN=256, BK=64, 8 waves
// (2x4 of 64x64), 512 threads, single LDS buffer. A converted f32->bf16 in
// staging (float4 loads + cvt_pk + swizzled ds_write), B via global_load_lds.
// Fused table rotary epilogue.
//  q: -> qkv cols 0..255 ; k: -> qkv 256..511 (chunk-swizzled) + kt[b][d][t]
//  v: -> vt[b][d][t] only.
// ---------------------------------------------------------------------------
__global__ __launch_bounds__(512, 2) void proj6_kernel(const float* __restrict__ x,
                                                       const unsigned short* __restrict__ wt,
                                                       const float* __restrict__ rt,
                                                       unsigned short* __restrict__ qkv,
                                                       unsigned short* __restrict__ kt,
                                                       unsigned short* __restrict__ vt) {
  __shared__ __align__(16) char smem[49152];  // As 16KB @0, Bs 32KB @16384
  unsigned short* As = (unsigned short*)smem;
  const int tid = threadIdx.x;
  const int lane = tid & 63;
  const int wid = tid >> 6;          // 0..7
  const int wr = wid >> 2, wc = wid & 3;
  const int m0 = blockIdx.x * 128;
  const int kind = blockIdx.y;       // 0:q 1:k 2:v
  const int l31 = lane & 31, lh = lane >> 5;

  // A-staging thread mapping: row 0..127, col group of 16 f32
  const int arow = tid >> 2;
  const int acg = (tid & 3) << 4;
  const int asw = (arow & 7) << 4;

  f32x16 acc[2][2];
#pragma unroll
  for (int i = 0; i < 2; ++i)
#pragma unroll
    for (int j = 0; j < 2; ++j) acc[i][j] = 0.0f;

  for (int k0 = 0; k0 < Hn; k0 += 64) {
    // ---- A: issue f32 loads early ----
    const float* srcA = x + (size_t)(m0 + arow) * 2048 + k0 + acg;
    float4 f0 = ((const float4*)srcA)[0];
    float4 f1 = ((const float4*)srcA)[1];
    float4 f2 = ((const float4*)srcA)[2];
    float4 f3 = ((const float4*)srcA)[3];
    // ---- B: async DMA to LDS ----
    {
      AS3 char* ldsb = (AS3 char*)(smem + 16384);
#pragma unroll
      for (int i = 0; i < 4; ++i) {
        int ou = i * 8192 + wid * 1024;
        int o = ou + lane * 16;
        int row = o >> 7, colB = o & 127;
        const char* srcB = (const char*)wt + (size_t)(kind * 256 + row) * 4096 + k0 * 2 + colB;
        __builtin_amdgcn_global_load_lds((const AS1 unsigned int*)srcB,
                                         (AS3 unsigned int*)(ldsb + ou), 16, 0, 0);
      }
    }
    // ---- A: convert + swizzled LDS write ----
    {
      uint4 u0, u1;
      asm("v_cvt_pk_bf16_f32 %0, %1, %2" : "=v"(u0.x) : "v"(f0.x), "v"(f0.y));
      asm("v_cvt_pk_bf16_f32 %0, %1, %2" : "=v"(u0.y) : "v"(f0.z), "v"(f0.w));
      asm("v_cvt_pk_bf16_f32 %0, %1, %2" : "=v"(u0.z) : "v"(f1.x), "v"(f1.y));
      asm("v_cvt_pk_bf16_f32 %0, %1, %2" : "=v"(u0.w) : "v"(f1.z), "v"(f1.w));
      asm("v_cvt_pk_bf16_f32 %0, %1, %2" : "=v"(u1.x) : "v"(f2.x), "v"(f2.y));
      asm("v_cvt_pk_bf16_f32 %0, %1, %2" : "=v"(u1.y) : "v"(f2.z), "v"(f2.w));
      asm("v_cvt_pk_bf16_f32 %0, %1, %2" : "=v"(u1.z) : "v"(f3.x), "v"(f3.y));
      asm("v_cvt_pk_bf16_f32 %0, %1, %2" : "=v"(u1.w) : "v"(f3.z), "v"(f3.w));
      *(uint4*)((char*)As + arow * 128 + ((acg * 2) ^ asw)) = u0;
      *(uint4*)((char*)As + arow * 128 + ((acg * 2 + 16) ^ asw)) = u1;
    }
    __syncthreads();
#pragma unroll
    for (int kc = 0; kc < 4; ++kc) {
      const int kb = kc * 32 + lh * 16;
      bf16x8 a[2], b[2];
#pragma unroll
      for (int i = 0; i < 2; ++i) {
        int mr = wr * 64 + i * 32 + l31;
        a[i] = *(const bf16x8*)((const char*)As + mr * 128 + (kb ^ ((mr & 7) << 4)));
        int nr = wc * 64 + i * 32 + l31;
        b[i] = *(const bf16x8*)(smem + 16384 + nr * 128 + (kb ^ ((nr & 7) << 4)));
      }
#pragma unroll
      for (int i = 0; i < 2; ++i)
#pragma unroll
        for (int j = 0; j < 2; ++j)
          acc[i][j] = __builtin_amdgcn_mfma_f32_32x32x16_bf16(a[i], b[j], acc[i][j], 0, 0, 0);
    }
    __syncthreads();
  }

  const int bidx = m0 >> 12;
  const int t0b = m0 & 4095;

  // ---- table rotary + scale for q/k ----
  if (kind < 2) {
    const float* rtb = rt + (size_t)kind * (4096 * 256);
    int jp[2];
#pragma unroll
    for (int j = 0; j < 2; ++j) jp[j] = (wc * 64 + j * 32 + l31) >> 1;
    const int odd = l31 & 1;
#pragma unroll
    for (int i = 0; i < 2; ++i)
#pragma unroll
      for (int reg = 0; reg < 16; ++reg) {
        const int mm = m0 + wr * 64 + i * 32 + (reg & 3) + 8 * (reg >> 2) + 4 * lh;
        const int s = mm & (Sn - 1);
#pragma unroll
        for (int j = 0; j < 2; ++j) {
          const float2 cf = *(const float2*)(rtb + (size_t)s * 256 + jp[j] * 2);
          float v = acc[i][j][reg];
          float p = __shfl_xor(v, 1, 64);
          acc[i][j][reg] = odd ? (v * cf.x + p * cf.y) : (v * cf.x - p * cf.y);
        }
      }
  }

  // ---- stores ----
  if (kind == 0) {
#pragma unroll
    for (int i = 0; i < 2; ++i)
#pragma unroll
      for (int j = 0; j < 2; ++j)
#pragma unroll
        for (int reg = 0; reg < 16; ++reg) {
          int m = m0 + wr * 64 + i * 32 + (reg & 3) + 8 * (reg >> 2) + 4 * lh;
          int n = wc * 64 + j * 32 + l31;
          qkv[(size_t)m * 768 + n] = f2bf(acc[i][j][reg]);
        }
  } else {
    if (kind == 1) {
#pragma unroll
      for (int i = 0; i < 2; ++i)
#pragma unroll
        for (int j = 0; j < 2; ++j)
#pragma unroll
          for (int reg = 0; reg < 16; ++reg) {
            int m = m0 + wr * 64 + i * 32 + (reg & 3) + 8 * (reg >> 2) + 4 * lh;
            int d = wc * 64 + j * 32 + l31;
            qkv[(size_t)m * 768 + 256 + (d ^ ((m & 7) << 3))] = f2bf(acc[i][j][reg]);
          }
    }
    // transpose via LDS (reuse GEMM LDS), two 128-d halves; waves with
    // (wc>>1)==h own half h.
    unsigned short* dst = (kind == 1) ? kt : vt;
#pragma unroll
    for (int h = 0; h < 2; ++h) {
      __syncthreads();
      if ((wc >> 1) == h) {
#pragma unroll
        for (int i = 0; i < 2; ++i)
#pragma unroll
          for (int j = 0; j < 2; ++j) {
            const int dl = (wc & 1) * 64 + j * 32 + l31;  // 0..127 within half
#pragma unroll
            for (int k8 = 0; k8 < 8; ++k8) {
              const int r0 = 2 * k8;
              const int t = wr * 64 + i * 32 + (r0 & 3) + 8 * (r0 >> 2) + 4 * lh;
              unsigned int pk;
              asm("v_cvt_pk_bf16_f32 %0, %1, %2" : "=v"(pk)
                  : "v"(acc[i][j][r0]), "v"(acc[i][j][r0 + 1]));
              *(unsigned int*)(smem + dl * 256 + ((2 * t) ^ ((dl & 7) << 4))) = pk;
            }
          }
      }
      __syncthreads();
#pragma unroll
      for (int p = 0; p < 4; ++p) {
        const int fl = p * 512 + tid;
        const int dl = fl >> 4, t8 = fl & 15;
        uint4 val = *(const uint4*)(smem + dl * 256 + ((t8 * 16) ^ ((dl & 7) << 4)));
        *(uint4*)(dst + (size_t)(bidx * 256 + h * 128 + dl) * 4096 + t0b + t8 * 8) = val;
      }
    }
  }
}

// ---------------------------------------------------------------------------
// wt_build (fallback path only)
// ---------------------------------------------------------------------------
__global__ __launch_bounds__(256) void wt_build(const float* __restrict__ wq,
                                                const float* __restrict__ wk,
                                                const float* __restrict__ wv,
                                                unsigned short* __restrict__ wt) {
  __shared__ __align__(16) unsigned short T[64][72];
  const int tid = threadIdx.x;
  const int k0 = blockIdx.x * 64;
  const int n0 = blockIdx.y * 64;
  const float* w = (n0 < 256) ? wq : (n0 < 512 ? wk : wv);
  const int nc0 = n0 & 255;
#pragma unroll
  for (int it = 0; it < 2; ++it) {
    int flat = it * 256 + tid;
    int r = flat >> 3, c8 = flat & 7;
    const float* src = w + (size_t)(k0 + r) * 256 + nc0 + c8 * 8;
    float4 v0 = *(const float4*)src;
    float4 v1 = *(const float4*)(src + 4);
    T[c8 * 8 + 0][r] = f2bf(v0.x); T[c8 * 8 + 1][r] = f2bf(v0.y);
    T[c8 * 8 + 2][r] = f2bf(v0.z); T[c8 * 8 + 3][r] = f2bf(v0.w);
    T[c8 * 8 + 4][r] = f2bf(v1.x); T[c8 * 8 + 5][r] = f2bf(v1.y);
    T[c8 * 8 + 6][r] = f2bf(v1.z); T[c8 * 8 + 7][r] = f2bf(v1.w);
  }
  __syncthreads();
#pragma unroll
  for (int it = 0; it < 2; ++it) {
    int flat = it * 256 + tid;
    int nr = flat >> 3, kc8 = flat & 7;
    int n = n0 + nr;
    int kc_sw = kc8 ^ (n & 7);
    uint4 val = *(const uint4*)&T[nr][kc8 * 8];
    *(uint4*)((char*)wt + (size_t)n * 4096 + (size_t)k0 * 2 + kc_sw * 16) = val;
  }
}

// ---------------------------------------------------------------------------
// proj (fallback small-ws): f32 A in-loop convert.
// ---------------------------------------------------------------------------
__global__ __launch_bounds__(256, 2) void proj_kernel(const float* __restrict__ x,
                                                      const unsigned short* __restrict__ wt,
                                                      unsigned short* __restrict__ qkv) {
  __shared__ __align__(16) unsigned short As[128 * 64];
  __shared__ __align__(16) unsigned short Bs[128 * 64];
  const int tid = threadIdx.x;
  const int lane = tid & 63;
  const int wid = tid >> 6;
  const int wr = wid >> 1, wc = wid & 1;
  const int m0 = blockIdx.x * 128;
  const int n0 = blockIdx.y * 128;
  const int l31 = lane & 31, lh = lane >> 5;

  f32x16 acc[2][2];
#pragma unroll
  for (int i = 0; i < 2; ++i)
#pragma unroll
    for (int j = 0; j < 2; ++j) acc[i][j] = 0.0f;

  for (int k0 = 0; k0 < Hn; k0 += 64) {
    {
      AS3 char* ldsb = (AS3 char*)Bs;
#pragma unroll
      for (int i = 0; i < 4; ++i) {
        int ou = i * 4096 + wid * 1024;
        int o = ou + lane * 16;
        int row = o >> 7, col = o & 127;
        const char* src = (const char*)wt + (size_t)(n0 + row) * 4096 + k0 * 2 + col;
        __builtin_amdgcn_global_load_lds((const AS1 unsigned int*)src,
                                         (AS3 unsigned int*)(ldsb + ou), 16, 0, 0);
      }
    }
#pragma unroll
    for (int i = 0; i < 4; ++i) {
      int o = i * 256 + tid;
      int row = o >> 3, c8 = o & 7;
      const float* src = x + (size_t)(m0 + row) * 2048 + k0 + c8 * 8;
      float4 v0 = *(const float4*)src;
      float4 v1 = *(const float4*)(src + 4);
      uint4 val;
      val.x = f2bf(v0.x) | ((unsigned int)f2bf(v0.y) << 16);
      val.y = f2bf(v0.z) | ((unsigned int)f2bf(v0.w) << 16);
      val.z = f2bf(v1.x) | ((unsigned int)f2bf(v1.y) << 16);
      val.w = f2bf(v1.z) | ((unsigned int)f2bf(v1.w) << 16);
      *(uint4*)((char*)As + row * 128 + ((c8 * 16) ^ ((row & 7) << 4))) = val;
    }
    __syncthreads();
#pragma unroll
    for (int kc = 0; kc < 4; ++kc) {
      const int kb = kc * 32 + lh * 16;
      bf16x8 a[2], b[2];
#pragma unroll
      for (int i = 0; i < 2; ++i) {
        int mr = wr * 64 + i * 32 + l31;
        a[i] = *(const bf16x8*)((const char*)As + mr * 128 + (kb ^ ((mr & 7) << 4)));
        int nr = wc * 64 + i * 32 + l31;
        b[i] = *(const bf16x8*)((const char*)Bs + nr * 128 + (kb ^ ((nr & 7) << 4)));
      }
#pragma unroll
      for (int i = 0; i < 2; ++i)
#pragma unroll
        for (int j = 0; j < 2; ++j)
          acc[i][j] = __builtin_amdgcn_mfma_f32_32x32x16_bf16(a[i], b[j], acc[i][j], 0, 0, 0);
    }
    __syncthreads();
  }
  const bool khalf = (n0 >= 256 && n0 < 512);
#pragma unroll
  for (int i = 0; i < 2; ++i)
#pragma unroll
    for (int j = 0; j < 2; ++j)
#pragma unroll
      for (int reg = 0; reg < 16; ++reg) {
        int m = m0 + wr * 64 + i * 32 + (reg & 3) + 8 * (reg >> 2) + 4 * lh;
        int n = n0 + wc * 64 + j * 32 + l31;
        if (khalf) n = 256 + ((n - 256) ^ ((m & 7) << 3));
        qkv[(size_t)m * 768 + n] = f2bf(acc[i][j][reg]);
      }
}

// ---------------------------------------------------------------------------
// xpos (fallback): rotary + chunk decay folding, in place on bf16 qkv.
// ---------------------------------------------------------------------------
__global__ __launch_bounds__(256) void xpos_kernel(unsigned short* __restrict__ qkv) {
  const int g = blockIdx.x * 256 + threadIdx.x;
  const int m = g >> 5;
  const int c = g & 31;
  const float s = (float)(m & (Sn - 1));
  unsigned short* qrow = qkv + (size_t)m * 768;
  const int csw = c ^ (m & 7);
  uint4 qv = *(uint4*)(qrow + c * 8);
  uint4 kv = *(uint4*)(qrow + 256 + csw * 8);
  unsigned int* qu = (unsigned int*)&qv;
  unsigned int* ku = (unsigned int*)&kv;
  const float pw = (s - 2048.0f) * (1.0f / 512.0f);
  const float gp = exp2f((float)(m & 255) * L2G);
#pragma unroll
  for (int p = 0; p < 4; ++p) {
    const int jp = c * 4 + p;
    const float invf = exp2f((float)jp * (-13.287712379549449f / 128.0f));
    float sn, cs;
    sincosf(s * invf, &sn, &cs);
    const float sv = (2.0f * jp + 102.4f) * (1.0f / 358.4f);
    const float scq = exp2f(pw * log2f(sv)) * gp;
    const float sci = 1.0f / scq;
    float q0 = bf2f(qu[p] & 0xffffu), q1 = bf2f(qu[p] >> 16);
    float k0 = bf2f(ku[p] & 0xffffu), k1 = bf2f(ku[p] >> 16);
    float q0r = (q0 * cs - q1 * sn) * scq;
    float q1r = (q1 * cs + q0 * sn) * scq;
    float k0r = (k0 * cs - k1 * sn) * sci;
    float k1r = (k1 * cs + k0 * sn) * sci;
    qu[p] = f2bf(q0r) | ((unsigned int)f2bf(q1r) << 16);
    ku[p] = f2bf(k0r) | ((unsigned int)f2bf(k1r) << 16);
  }
  *(uint4*)(qrow + c * 8) = qv;
  *(uint4*)(qrow + 256 + csw * 8) = kv;
}

// ---------------------------------------------------------------------------
// kvt (fallback): kt[b][d][t], vt[b][d][t] from qkv.
// ---------------------------------------------------------------------------
__global__ __launch_bounds__(256) void kvt_build(const unsigned short* __restrict__ qkv,
                                                 unsigned short* __restrict__ kt,
                                                 unsigned short* __restrict__ vt) {
  __shared__ __align__(16) unsigned short Tk[64][72];
  __shared__ __align__(16) unsigned short Tv[64][72];
  const int tid = threadIdx.x;
  const int t0 = blockIdx.x * 64;
  const int d0 = blockIdx.y * 64;
  const int b = blockIdx.z;
  const size_t rowb = ((size_t)b * Sn + t0) * 1536;
#pragma unroll
  for (int it = 0; it < 2; ++it) {
    int flat = it * 256 + tid;
    int r = flat >> 3, c8 = flat & 7;
    int kc = (d0 >> 3) + c8;
    int kcs = kc ^ (r & 7);
    uint4 kvv = *(const uint4*)((const char*)qkv + rowb + (size_t)r * 1536 + 512 + kcs * 16);
    uint4 vvv = *(const uint4*)((const char*)qkv + rowb + (size_t)r * 1536 + 1024 + (size_t)(d0 + c8 * 8) * 2);
    const unsigned short* ke = (const unsigned short*)&kvv;
    const unsigned short* ve = (const unsigned short*)&vvv;
#pragma unroll
    for (int e = 0; e < 8; ++e) { Tk[c8 * 8 + e][r] = ke[e]; Tv[c8 * 8 + e][r] = ve[e]; }
  }
  __syncthreads();
#pragma unroll
  for (int it = 0; it < 2; ++it) {
    int flat = it * 256 + tid;
    int dr = flat >> 3, tc8 = flat & 7;
    *(uint4*)(kt + (size_t)(b * 256 + d0 + dr) * 4096 + t0 + tc8 * 8) = *(const uint4*)&Tk[dr][tc8 * 8];
    *(uint4*)(vt + (size_t)(b * 256 + d0 + dr) * 4096 + t0 + tc8 * 8) = *(const uint4*)&Tv[dr][tc8 * 8];
  }
}

// ---------------------------------------------------------------------------
// mbuild: Mt[b][j][d2][d1] = sum_t V[t][d2] * K~[t][d1], bf16 out.
// ---------------------------------------------------------------------------
__global__ __launch_bounds__(256) void mbuild_kernel(const unsigned short* __restrict__ kt,
                                                     const unsigned short* __restrict__ vt,
                                                     unsigned short* __restrict__ mt) {
  const int tid = threadIdx.x;
  const int lane = tid & 63;
  const int wid = tid >> 6;
  const int l31 = lane & 31, lh = lane >> 5;
  const int jc = blockIdx.x;
  const int quad = blockIdx.y;
  const int b = blockIdx.z;
  const int d2w = ((quad >> 1) * 2 + (wid >> 1)) * 64;
  const int d1w = ((quad & 1) * 2 + (wid & 1)) * 64;
  const size_t tb = (size_t)jc * 256;

  f32x16 acc[2][2];
#pragma unroll
  for (int i = 0; i < 2; ++i)
#pragma unroll
    for (int j = 0; j < 2; ++j) acc[i][j] = 0.0f;

#pragma unroll 2
  for (int dc = 0; dc < 16; ++dc) {
    const int ko = dc * 32 + lh * 16;
    bf16x8 a[2], bb[2];
#pragma unroll
    for (int i = 0; i < 2; ++i) {
      a[i]  = *(const bf16x8*)((const char*)vt + ((size_t)(b * 256 + d2w + i * 32 + l31) * 4096 + tb) * 2 + ko);
      bb[i] = *(const bf16x8*)((const char*)kt + ((size_t)(b * 256 + d1w + i * 32 + l31) * 4096 + tb) * 2 + ko);
    }
#pragma unroll
    for (int i = 0; i < 2; ++i)
#pragma unroll
      for (int j = 0; j < 2; ++j)
        acc[i][j] = __builtin_amdgcn_mfma_f32_32x32x16_bf16(a[i], bb[j], acc[i][j], 0, 0, 0);
  }
  unsigned short* dst = mt + ((size_t)(b * 16 + jc) << 16);
#pragma unroll
  for (int i = 0; i < 2; ++i)
#pragma unroll
    for (int j = 0; j < 2; ++j)
#pragma unroll
      for (int reg = 0; reg < 16; ++reg) {
        int row = d2w + i * 32 + (reg & 3) + 8 * (reg >> 2) + 4 * lh;
        int col = d1w + j * 32 + l31;
        dst[row * 256 + col] = f2bf(acc[i][j][reg]);
      }
}

// ---------------------------------------------------------------------------
// scan: S_j = GC*(S_{j-1} + M_{j-1}), in place to slot j-1 (bf16).
// ---------------------------------------------------------------------------
__global__ __launch_bounds__(256) void scan_kernel(unsigned short* __restrict__ mt) {
  const int e0 = (blockIdx.x * 256 + threadIdx.x) * 4;
  const int b = blockIdx.y;
  unsigned short* base = mt + ((size_t)b << 20);
  float s0 = 0.f, s1 = 0.f, s2 = 0.f, s3 = 0.f;
  for (int j = 1; j < 16; ++j) {
    unsigned short* p = base + ((size_t)(j - 1) << 16) + e0;
    uint2 mv = *(const uint2*)p;
    s0 = GC * (s0 + bf2f(mv.x & 0xffffu));
    s1 = GC * (s1 + bf2f(mv.x >> 16));
    s2 = GC * (s2 + bf2f(mv.y & 0xffffu));
    s3 = GC * (s3 + bf2f(mv.y >> 16));
    uint2 w;
    w.x = f2bf(s0) | ((unsigned int)f2bf(s1) << 16);
    w.y = f2bf(s2) | ((unsigned int)f2bf(s3) << 16);
    *(uint2*)p = w;
  }
}

// ---------------------------------------------------------------------------
// retc: out = Q~ @ S_j (cross) + causal-intra(Q~ K~^T) @ V
// Grid (128 st32, 2 dh, 4 b) = 1024 blocks; 4 waves split cross-dc /
// intra-parity. Two-stage LDS combine. (R7-proven configuration.)
// ---------------------------------------------------------------------------
__global__ __launch_bounds__(256, 2) void retc_kernel(const unsigned short* __restrict__ qkv,
                                                      const unsigned short* __restrict__ vt,
                                                      const unsigned short* __restrict__ mt,
                                                      float* __restrict__ out) {
  __shared__ float cmb[2][32][128];
  const int tid = threadIdx.x;
  const int lane = tid & 63;
  const int tw = tid >> 6;
  const int l31 = lane & 31, lh = lane >> 5;
  const int st = blockIdx.x;
  const int dh = blockIdx.y;
  const int b = blockIdx.z;
  const int j = st >> 3;
  const int base = st & ~7;
  const int s0 = st * 32;
  const int d0 = dh * 128;

  bf16x8 qf[16];
  {
    const char* qrow = (const char*)qkv + ((size_t)b * Sn + s0 + l31) * 1536;
#pragma unroll
    for (int dc = 0; dc < 16; ++dc)
      qf[dc] = *(const bf16x8*)(qrow + dc * 32 + lh * 16);
  }

  f32x16 acc[4];
#pragma unroll
  for (int i = 0; i < 4; ++i) acc[i] = 0.0f;

  if (j > 0) {
    const char* Sj = (const char*)mt + ((size_t)(b * 16 + j - 1) << 17);
#pragma unroll
    for (int dcl = 0; dcl < 4; ++dcl) {
      const int dc = tw * 4 + dcl;
#pragma unroll
      for (int g = 0; g < 4; ++g) {
        const int d2 = d0 + g * 32 + l31;
        bf16x8 sbf = *(const bf16x8*)(Sj + (size_t)d2 * 512 + dc * 32 + lh * 16);
        acc[g] = __builtin_amdgcn_mfma_f32_32x32x16_bf16(qf[dc], sbf, acc[g], 0, 0, 0);
      }
    }
  }

  const int sg = s0 + l31;
  const int ksw = (l31 & 7) << 4;
  for (int tt = base; tt <= st; ++tt) {
    if (((tt - base) & 3) != tw) continue;
    const bool msk = (tt == st);
    const int t0 = tt * 32;

    f32x16 sacc = 0.0f;
    const char* krow = (const char*)qkv + ((size_t)b * Sn + t0 + l31) * 1536 + 512;
    __builtin_amdgcn_s_setprio(1);
#pragma unroll
    for (int dc = 0; dc < 16; ++dc) {
      bf16x8 kf = *(const bf16x8*)(krow + ((dc * 32 + lh * 16) ^ ksw));
      sacc = __builtin_amdgcn_mfma_f32_32x32x16_bf16(kf, qf[dc], sacc, 0, 0, 0);
    }
    __builtin_amdgcn_s_setprio(0);

    unsigned int P[8];
#pragma unroll
    for (int k = 0; k < 8; ++k) {
      const int r0 = 2 * k;
      float f0 = sacc[r0], f1 = sacc[r0 + 1];
      if (msk) {
        const int tg0 = t0 + (r0 & 3) + 8 * (r0 >> 2) + 4 * lh;
        f0 = (sg - tg0 >= 0) ? f0 : 0.0f;
        f1 = (sg - tg0 - 1 >= 0) ? f1 : 0.0f;
      }
      unsigned int pk;
      asm("v_cvt_pk_bf16_f32 %0, %1, %2" : "=v"(pk) : "v"(f0), "v"(f1));
      P[k] = pk;
    }
    asm volatile("v_permlane32_swap_b32 %0, %1" : "+v"(P[0]), "+v"(P[2]));
    asm volatile("v_permlane32_swap_b32 %0, %1" : "+v"(P[1]), "+v"(P[3]));
    asm volatile("v_permlane32_swap_b32 %0, %1" : "+v"(P[4]), "+v"(P[6]));
    asm volatile("v_permlane32_swap_b32 %0, %1" : "+v"(P[5]), "+v"(P[7]));

    __builtin_amdgcn_s_setprio(1);
#pragma unroll
    for (int kc = 0; kc < 2; ++kc) {
      uint4 pw;
      pw.x = P[kc * 4 + 0]; pw.y = P[kc * 4 + 1];
      pw.z = P[kc * 4 + 2]; pw.w = P[kc * 4 + 3];
      bf16x8 pf = *(const bf16x8*)&pw;
#pragma unroll
      for (int g = 0; g < 4; ++g) {
        const int d = d0 + g * 32 + l31;
        bf16x8 vf = *(const bf16x8*)((const char*)vt +
            ((size_t)(b * 256 + d) * 4096 + t0) * 2 + kc * 32 + lh * 16);
        acc[g] = __builtin_amdgcn_mfma_f32_32x32x16_bf16(pf, vf, acc[g], 0, 0, 0);
      }
    }
    __builtin_amdgcn_s_setprio(0);
  }

  if (tw >= 2) {
#pragma unroll
    for (int g = 0; g < 4; ++g)
#pragma unroll
      for (int reg = 0; reg < 16; ++reg) {
        int sl = (reg & 3) + 8 * (reg >> 2) + 4 * lh;
        cmb[tw - 2][sl][g * 32 + l31] = acc[g][reg];
      }
  }
  __syncthreads();
  if (tw < 2) {
#pragma unroll
    for (int g = 0; g < 4; ++g)
#pragma unroll
      for (int reg = 0; reg < 16; ++reg) {
        int sl = (reg & 3) + 8 * (reg >> 2) + 4 * lh;
        acc[g][reg] += cmb[tw][sl][g * 32 + l31];
      }
  }
  __syncthreads();
  if (tw == 1) {
#pragma unroll
    for (int g = 0; g < 4; ++g)
#pragma unroll
      for (int reg = 0; reg < 16; ++reg) {
        int sl = (reg & 3) + 8 * (reg >> 2) + 4 * lh;
        cmb[0][sl][g * 32 + l31] = acc[g][reg];
      }
  }
  __syncthreads();
  if (tw == 0) {
#pragma unroll
    for (int g = 0; g < 4; ++g)
#pragma unroll
      for (int reg = 0; reg < 16; ++reg) {
        int sl = (reg & 3) + 8 * (reg >> 2) + 4 * lh;
        int c = g * 32 + l31;
        out[((size_t)(b * Sn + s0 + sl)) * 256 + d0 + c] = acc[g][reg] + cmb[0][sl][c];
      }
  }
}

// ---------------------------------------------------------------------------
extern "C" void kernel_launch(void* const* d_in, const int* in_sizes, int n_in,
                              void* d_out, int out_size, void* d_ws, size_t ws_size,
                              hipStream_t stream) {
  (void)in_sizes; (void)n_in; (void)out_size;
  const float* x  = (const float*)d_in[0];
  const float* wq = (const float*)d_in[1];
  const float* wk = (const float*)d_in[2];
  const float* wv = (const float*)d_in[3];
  float* out = (float*)d_out;
  char* ws = (char*)d_ws;

  unsigned short* qkv = (unsigned short*)(ws);              // 25,165,824 B
  unsigned short* vt  = (unsigned short*)(ws + 25165824);   //  8,388,608 B
  unsigned short* kt  = (unsigned short*)(ws + 33554432);   //  8,388,608 B
  unsigned short* mt  = (unsigned short*)(ws + 41943040);   //  8,388,608 B

  const size_t NEED_BIG = 128974848;  // wt@117440512 + rt@120586240
  if (ws_size >= NEED_BIG) {
    unsigned short* wt = (unsigned short*)(ws + 117440512);  //  3,145,728 B
    float*          rtab = (float*)(ws + 120586240);         //  8,388,608 B
    prep_kernel<<<2432, 256, 0, stream>>>(wq, wk, wv, wt, rtab);
    proj6_kernel<<<dim3(128, 3), 512, 0, stream>>>(x, wt, rtab, qkv, kt, vt);
  } else {
    unsigned short* wt = (unsigned short*)(ws + 41943040);  // alias mt (dead before mbuild)
    wt_build<<<dim3(32, 12), 256, 0, stream>>>(wq, wk, wv, wt);
    proj_kernel<<<dim3(128, 6), 256, 0, stream>>>(x, wt, qkv);
    xpos_kernel<<<2048, 256, 0, stream>>>(qkv);
    kvt_build<<<dim3(64, 4, 4), 256, 0, stream>>>(qkv, kt, vt);
  }
  mbuild_kernel<<<dim3(16, 4, 4), 256, 0, stream>>>(kt, vt, mt);
  scan_kernel<<<dim3(64, 4), 256, 0, stream>>>(mt);
  retc_kernel<<<dim3(128, 2, 4), 256, 0, stream>>>(qkv, vt, mt, out);
}